// Round 6
// baseline (250.882 us; speedup 1.0000x reference)
//
#include <hip/hip_runtime.h>

// Problem constants: B=4, C=3, H=512, W=960, K2=16 -> K=4
#define BB 4
#define CC 3
#define HH 512
#define WW 960
#define HW (HH * WW)
#define YD 4                    // y-depth: pixels per thread (vertical column)
#define NTX (WW / 64)           // 15 x-tiles
#define NTG (HH / (4 * YD))     // 32 y-supertiles (4 waves x YD rows)

typedef float f4 __attribute__((ext_vector_type(4)));

__global__ __launch_bounds__(256, 2)
void filter_interp_col(const float* __restrict__ inp,
                       const float* __restrict__ flow,
                       const float* __restrict__ filt,
                       float* __restrict__ out) {
    const int lx = threadIdx.x & 63;
    const int ly = threadIdx.x >> 6;
    int blk = blockIdx.x;
    const int b  = blk / (NTG * NTX);
    int r        = blk - b * (NTG * NTX);
    const int tg = r / NTX;
    const int tx = r - tg * NTX;

    const int x  = tx * 64 + lx;
    const int y0 = tg * (4 * YD) + ly * YD;

    const float* flb = flow + (size_t)(b * 2) * HW;
    const float* fb  = filt + (size_t)(b * 16) * HW;
    const float* ib  = inp  + (size_t)(b * CC) * HW;
    float*       ob  = out  + (size_t)(b * CC) * HW;

    // ---- Hoist ALL iterations' flow + filter loads (coalesced, independent;
    //      4 separate dependency chains the scheduler can interleave) ----
    float fxv[YD], fyv[YD], ftv[YD][16];
#pragma unroll
    for (int k = 0; k < YD; ++k) {
        const int rem = (y0 + k) * WW + x;
        fxv[k] = flb[rem];
        fyv[k] = flb[rem + HW];
#pragma unroll
        for (int t = 0; t < 16; ++t) ftv[k][t] = fb[(size_t)t * HW + rem];
    }

#pragma unroll
    for (int k = 0; k < YD; ++k) {
        const int y   = y0 + k;
        const int rem = y * WW + x;
        const float fx = fxv[k];
        const float fy = fyv[k];

        const float x2 = (float)x + fx;
        const float y2 = (float)y + fy;
        const bool valid = (x2 >= 0.0f) && (x2 <= (float)(WW - 1)) &&
                           (y2 >= 0.0f) && (y2 <= (float)(HH - 1)) &&
                           (fabsf(fx) < (float)WW * 0.5f) &&
                           (fabsf(fy) < (float)HH * 0.5f);

        const float fxf = floorf(x2);
        const float fyf = floorf(y2);
        // Branchless sanitize: invalid lanes use safe in-range addresses,
        // weights become 0.
        const float alpha = valid ? (x2 - fxf) : 0.0f;
        const float beta  = valid ? (y2 - fyf) : 0.0f;
        const int   ix    = valid ? (int)fxf : 480;
        const int   iy    = valid ? (int)fyf : 256;
        const float vf    = valid ? 1.0f : 0.0f;

        const float wTL = vf * (1.0f - alpha) * (1.0f - beta);
        const float wTR = vf * alpha * (1.0f - beta);
        const float wBL = vf * (1.0f - alpha) * beta;
        const float wBR = vf * alpha * beta;

        const int ixL0 = ix - 1;
        const int iyT0 = iy - 1;
        int R[5];
#pragma unroll
        for (int j = 0; j < 5; ++j) R[j] = min(max(iyT0 + j, 0), HH - 1);

        f4 acc4[CC];
#pragma unroll
        for (int c = 0; c < CC; ++c) acc4[c] = (f4){0.f, 0.f, 0.f, 0.f};
        float accs[CC] = {0.f, 0.f, 0.f};

        const bool fast = (ixL0 >= 0) && (ixL0 <= WW - 5);
        if (fast) {
            const int a0 = ixL0 & ~3;
            const int o  = ixL0 - a0;

            // Issue all 30 patch loads of this pixel before consumption.
            f4 P[30];
#pragma unroll
            for (int j = 0; j < 5; ++j) {
                const int ro = R[j] * WW + a0;
#pragma unroll
                for (int c = 0; c < CC; ++c) {
                    const float* p = ib + (size_t)c * HW + ro;
                    P[(j * 3 + c) * 2 + 0] = *(const f4*)(p);
                    P[(j * 3 + c) * 2 + 1] = *(const f4*)(p + 4);
                }
            }

            // Weight fold (overlaps patch-load flight).
            float Wm[5][5];
#pragma unroll
            for (int j = 0; j < 5; ++j)
#pragma unroll
                for (int i = 0; i < 5; ++i) Wm[j][i] = 0.0f;
#pragma unroll
            for (int dj = 0; dj < 4; ++dj) {
#pragma unroll
                for (int di = 0; di < 4; ++di) {
                    const float f = ftv[k][dj * 4 + di];
                    Wm[dj][di]         += f * wTL;
                    Wm[dj][di + 1]     += f * wTR;
                    Wm[dj + 1][di]     += f * wBL;
                    Wm[dj + 1][di + 1] += f * wBR;
                }
            }

            // Barrel-shift weight rows into two f4 windows per row.
            const bool s2 = (o & 2) != 0;
            const bool s1 = (o & 1) != 0;
            f4 WL[5], WH[5];
#pragma unroll
            for (int j = 0; j < 5; ++j) {
                float t[8];
#pragma unroll
                for (int i = 0; i < 8; ++i) t[i] = (i < 5) ? Wm[j][i] : 0.0f;
                float u[8];
#pragma unroll
                for (int i = 0; i < 8; ++i)
                    u[i] = s2 ? ((i >= 2) ? t[i - 2] : 0.0f) : t[i];
                float w[8];
#pragma unroll
                for (int i = 0; i < 8; ++i)
                    w[i] = s1 ? ((i >= 1) ? u[i - 1] : 0.0f) : u[i];
                WL[j] = (f4){w[0], w[1], w[2], w[3]};
                WH[j] = (f4){w[4], w[5], w[6], w[7]};
            }

#pragma unroll
            for (int j = 0; j < 5; ++j) {
#pragma unroll
                for (int c = 0; c < CC; ++c) {
                    acc4[c] += P[(j * 3 + c) * 2 + 0] * WL[j];
                    acc4[c] += P[(j * 3 + c) * 2 + 1] * WH[j];
                }
            }
        } else {
            // Rare slow path (window crosses horizontal border).
            float Wm[5][5];
#pragma unroll
            for (int j = 0; j < 5; ++j)
#pragma unroll
                for (int i = 0; i < 5; ++i) Wm[j][i] = 0.0f;
#pragma unroll
            for (int dj = 0; dj < 4; ++dj) {
#pragma unroll
                for (int di = 0; di < 4; ++di) {
                    const float f = ftv[k][dj * 4 + di];
                    Wm[dj][di]         += f * wTL;
                    Wm[dj][di + 1]     += f * wTR;
                    Wm[dj + 1][di]     += f * wBL;
                    Wm[dj + 1][di + 1] += f * wBR;
                }
            }
            int S[5];
#pragma unroll
            for (int i = 0; i < 5; ++i) S[i] = min(max(ixL0 + i, 0), WW - 1);
#pragma unroll
            for (int c = 0; c < CC; ++c) {
                const float* ic = ib + (size_t)c * HW;
                float a = 0.0f;
#pragma unroll
                for (int j = 0; j < 5; ++j) {
                    const float* row = ic + (size_t)R[j] * WW;
#pragma unroll
                    for (int i = 0; i < 5; ++i) a += row[S[i]] * Wm[j][i];
                }
                accs[c] = a;
            }
        }

#pragma unroll
        for (int c = 0; c < CC; ++c) {
            ob[(size_t)c * HW + rem] =
                acc4[c][0] + acc4[c][1] + acc4[c][2] + acc4[c][3] + accs[c];
        }
    }
}

extern "C" void kernel_launch(void* const* d_in, const int* in_sizes, int n_in,
                              void* d_out, int out_size, void* d_ws, size_t ws_size,
                              hipStream_t stream) {
    const float* teninput  = (const float*)d_in[0];
    const float* tenflow   = (const float*)d_in[1];
    const float* tenfilter = (const float*)d_in[2];
    float* out = (float*)d_out;

    const int blocks = BB * NTG * NTX;  // 4 * 32 * 15 = 1920
    filter_interp_col<<<blocks, 256, 0, stream>>>(teninput, tenflow, tenfilter, out);
}